// Round 8
// baseline (1712.232 us; speedup 1.0000x reference)
//
#include <hip/hip_runtime.h>

#define NGRAPH 16384
#define NPG    9
#define DM     128
#define NLAY   4
#define EPG    16
#define GPB    28
#define RPB    256
#define NBLK   586   /* ceil(16384/28) */

typedef __attribute__((ext_vector_type(8))) short bf16x8;
typedef __attribute__((ext_vector_type(4))) float f32x4;

__device__ __forceinline__ float b2f(unsigned short u){
  union { unsigned int i; float f; } v; v.i = ((unsigned int)u) << 16; return v.f;
}
__device__ __forceinline__ unsigned short f2b(float f){
  union { float fv; unsigned int i; } v; v.fv = f;
  unsigned int r = v.i + 0x7FFFu + ((v.i >> 16) & 1u);
  return (unsigned short)(r >> 16);
}

__device__ __forceinline__ bf16x8 ldfrag(const unsigned short* buf, int row, int kk, int g16){
  return *(const bf16x8*)&buf[row*DM + ((kk*32 + g16*8) ^ ((row & 7) << 3))];
}
__device__ __forceinline__ f32x4 mfma16(bf16x8 a, bf16x8 b, f32x4 c){
  return __builtin_amdgcn_mfma_f32_16x16x32_bf16(a, b, c, 0, 0, 0);
}

// 64x128x128 per-wave GEMM: A from LDS (swizzled rows, wave owns 64 rows),
// B from global fragment-linear tile (frag f = kk*8+nt, 64 lanes x 16B).
// kk fully unrolled; each B-frag feeds 4 MFMAs. 1 wave/SIMD -> ~512-reg budget.
__device__ __forceinline__ void gemm64(const unsigned short* __restrict__ A,
                                       const unsigned short* __restrict__ Bt,
                                       int rbase, int l15, int g16, int lane,
                                       f32x4 (&acc)[4][8])
{
  const bf16x8* Bf = (const bf16x8*)Bt;
  #pragma unroll
  for (int kk = 0; kk < 4; ++kk){
    bf16x8 a0 = ldfrag(A, rbase +      l15, kk, g16);
    bf16x8 a1 = ldfrag(A, rbase + 16 + l15, kk, g16);
    bf16x8 a2 = ldfrag(A, rbase + 32 + l15, kk, g16);
    bf16x8 a3 = ldfrag(A, rbase + 48 + l15, kk, g16);
    __builtin_amdgcn_s_setprio(1);
    #pragma unroll
    for (int nt = 0; nt < 8; ++nt){
      bf16x8 bb = Bf[(kk*8 + nt)*64 + lane];
      acc[0][nt] = mfma16(a0, bb, acc[0][nt]);
      acc[1][nt] = mfma16(a1, bb, acc[1][nt]);
      acc[2][nt] = mfma16(a2, bb, acc[2][nt]);
      acc[3][nt] = mfma16(a3, bb, acc[3][nt]);
    }
    __builtin_amdgcn_s_setprio(0);
  }
}

// Weight pre-transform: f32 -> bf16, transposed, fragment-linear.
// 36 tiles of 16384 bf16: per layer l: [0]=WgT, [1..4]=W1T col-chunk c, [5..8]=W2T k-chunk c.
// frag (kk,nt), lane, e: value = W[k = kk*32 + (lane>>4)*8 + e][n = nt*16 + (lane&15)]
// stored at tile*16384 + (kk*8+nt)*512 + lane*8 + e.
__global__ void wtr_kernel(const float* __restrict__ Wg,
                           const float* __restrict__ W1,
                           const float* __restrict__ W2,
                           unsigned short* __restrict__ wsT){
  int idx = blockIdx.x * 256 + threadIdx.x;   // 288 blocks -> 73728 threads
  int lane = idx & 63;
  int f = (idx >> 6) & 31;
  int t = idx >> 11;
  if (t >= 36) return;
  int kk = f >> 3, nt = f & 7;
  int n  = nt*16 + (lane & 15);
  int k0 = kk*32 + (lane >> 4)*8;
  int l = t / 9, t9 = t - l*9;
  bf16x8 o;
  #pragma unroll
  for (int e = 0; e < 8; ++e){
    int k = k0 + e;
    float v;
    if (t9 == 0)      v = Wg[l*16384 + k*128 + n];
    else if (t9 < 5)  v = W1[l*65536 + k*512 + (t9-1)*128 + n];
    else              v = W2[l*65536 + ((t9-5)*128 + k)*128 + n];
    o[e] = (short)f2b(v);
  }
  *(bf16x8*)&wsT[t*16384 + f*512 + lane*8] = o;
}

__global__ void __launch_bounds__(256, 1)
gcn_kernel(const float* __restrict__ op_table,
           const float* __restrict__ dev_emb,
           const float* __restrict__ bgp,
           const float* __restrict__ lngp,
           const float* __restrict__ lnbp,
           const float* __restrict__ b1p,
           const float* __restrict__ b2p,
           const float* __restrict__ fcw,
           const float* __restrict__ fcb,
           const int* __restrict__ op_idx,
           const int* __restrict__ srcA,
           const int* __restrict__ dstA,
           const unsigned short* __restrict__ wsT,
           float* __restrict__ out)
{
  __shared__ unsigned short hbuf[RPB*DM];      // natural h; aliased as swizzled Hc in FFN
  __shared__ unsigned short Abuf[RPB*DM];      // swizzled A operand (agg, then X)
  __shared__ float cntF[GPB][81];              // normalized adjacency (isd folded in)
  __shared__ float isd_s[RPB];
  __shared__ float bg_s[DM], lng_s[DM], lnb_s[DM], b2_s[DM];
  __shared__ float b1_s[4*DM];

  const int tid  = threadIdx.x;
  const int w    = tid >> 6;
  const int lane = tid & 63;
  const int g16  = lane >> 4;
  const int l15  = lane & 15;
  const int rbase = w * 64;                    // wave owns 64 rows
  const int g0 = blockIdx.x * GPB;
  const int nvalid = (NGRAPH - g0 < GPB) ? (NGRAPH - g0) : GPB;

  // ---------------- preamble ----------------
  for (int i = tid; i < GPB*81; i += 256) (&cntF[0][0])[i] = 0.f;

  { // h0 = op_table[idx] + device_emb (f32 -> bf16); one FULL row (128) per thread
    int r  = tid;
    int gi = r / NPG;
    int j  = r - gi*NPG;
    bf16x8* dstp = (bf16x8*)&hbuf[r*DM];
    if (r < GPB*NPG && gi < nvalid) {
      int idx = op_idx[(g0 + gi)*NPG + j];
      const float4* ot = (const float4*)&op_table[idx*DM];
      const float4* de = (const float4*)&dev_emb[0];
      #pragma unroll
      for (int i = 0; i < 16; ++i){
        float4 a0 = ot[2*i], a1 = ot[2*i+1];
        float4 d0 = de[2*i], d1 = de[2*i+1];
        bf16x8 o;
        o[0] = (short)f2b(a0.x + d0.x); o[1] = (short)f2b(a0.y + d0.y);
        o[2] = (short)f2b(a0.z + d0.z); o[3] = (short)f2b(a0.w + d0.w);
        o[4] = (short)f2b(a1.x + d1.x); o[5] = (short)f2b(a1.y + d1.y);
        o[6] = (short)f2b(a1.z + d1.z); o[7] = (short)f2b(a1.w + d1.w);
        dstp[i] = o;
      }
    } else {
      bf16x8 z;
      #pragma unroll
      for (int q = 0; q < 8; ++q) z[q] = 0;
      #pragma unroll
      for (int i = 0; i < 16; ++i) dstp[i] = z;
    }
  }
  __syncthreads();

  if (tid < GPB) { // per-graph 9x9 count matrix (incl. self loops) + isd
    if (tid < nvalid) {
      float* c = cntF[tid];
      for (int e = 0; e < EPG; ++e){
        int s = srcA[(g0 + tid)*EPG + e];
        int d = dstA[(g0 + tid)*EPG + e];
        c[(s % NPG)*NPG + (d % NPG)] += 1.f;
      }
      #pragma unroll
      for (int j = 0; j < NPG; ++j) c[j*NPG + j] += 1.f;
      #pragma unroll
      for (int jd = 0; jd < NPG; ++jd){
        float s = 0.f;
        #pragma unroll
        for (int js = 0; js < NPG; ++js) s += c[js*NPG + jd];
        isd_s[tid*NPG + jd] = rsqrtf(s);
      }
    } else {
      #pragma unroll
      for (int jd = 0; jd < NPG; ++jd) isd_s[tid*NPG + jd] = 1.f;
    }
  }
  __syncthreads();

  // fold isd into cnt once: cnt'[js][jd] = cnt * isd[js] * isd[jd]
  for (int idx = tid; idx < GPB*81; idx += 256){
    int gi = idx / 81;
    int e  = idx - gi*81;
    int js = e / 9, jd = e - js*9;
    (&cntF[0][0])[idx] *= isd_s[gi*NPG + js] * isd_s[gi*NPG + jd];
  }
  __syncthreads();

  #pragma unroll 1
  for (int l = 0; l < NLAY; ++l){
    // ---------- Phase A: biases + aggregation -> Abuf (cross-wave) ----------
    if (tid < DM) {
      bg_s[tid]  = bgp [l*DM + tid];
      lng_s[tid] = lngp[l*DM + tid];
      lnb_s[tid] = lnbp[l*DM + tid];
      b2_s[tid]  = b2p [l*DM + tid];
    }
    b1_s[tid]       = b1p[l*4*DM + tid];
    b1_s[tid + 256] = b1p[l*4*DM + 256 + tid];
    {
      int gi = tid >> 3;
      int cb = (tid & 7) * 16;
      if (gi < GPB) {
        #pragma unroll
        for (int hh = 0; hh < 2; ++hh){
          int f0 = cb + hh*8;
          float hs[NPG][8];
          #pragma unroll
          for (int j = 0; j < NPG; ++j){
            bf16x8 hv = *(const bf16x8*)&hbuf[(gi*NPG + j)*DM + f0];
            #pragma unroll
            for (int i = 0; i < 8; ++i) hs[j][i] = b2f((unsigned short)hv[i]);
          }
          #pragma unroll
          for (int jd = 0; jd < NPG; ++jd){
            float av[8];
            #pragma unroll
            for (int i = 0; i < 8; ++i) av[i] = 0.f;
            #pragma unroll
            for (int js = 0; js < NPG; ++js){
              float cc = cntF[gi][js*NPG + jd];
              #pragma unroll
              for (int i = 0; i < 8; ++i) av[i] = fmaf(cc, hs[js][i], av[i]);
            }
            int row = gi*NPG + jd;
            bf16x8 o;
            #pragma unroll
            for (int i = 0; i < 8; ++i) o[i] = (short)f2b(av[i]);
            *(bf16x8*)&Abuf[row*DM + (f0 ^ ((row & 7) << 3))] = o;
          }
        }
      } else { // zero pad rows 252..255 (32 threads x 16 cols each)
        int k2 = tid - GPB*8;
        int row = GPB*NPG + (k2 >> 3);
        int f0 = (tid & 7) * 16;
        bf16x8 z;
        #pragma unroll
        for (int q = 0; q < 8; ++q) z[q] = 0;
        *(bf16x8*)&Abuf[row*DM + (f0 ^ ((row & 7) << 3))] = z;
        *(bf16x8*)&Abuf[row*DM + ((f0 + 8) ^ ((row & 7) << 3))] = z;
      }
    }
    __syncthreads();   // barrier A: agg + biases visible to all waves

    // ---------- GCN GEMM + ReLU + LN -> X (wave-local from here on) ----------
    {
      f32x4 acc[4][8];
      #pragma unroll
      for (int mt = 0; mt < 4; ++mt)
        #pragma unroll
        for (int nt = 0; nt < 8; ++nt){ f32x4 z; z[0]=z[1]=z[2]=z[3]=0.f; acc[mt][nt]=z; }
      gemm64(Abuf, wsT + (l*9)*16384, rbase, l15, g16, lane, acc);

      #pragma unroll
      for (int mt = 0; mt < 4; ++mt){
        float rs[4], rq[4];
        #pragma unroll
        for (int j = 0; j < 4; ++j){ rs[j] = 0.f; rq[j] = 0.f; }
        #pragma unroll
        for (int nt = 0; nt < 8; ++nt){
          #pragma unroll
          for (int j = 0; j < 4; ++j){
            float v = acc[mt][nt][j] + bg_s[nt*16 + l15];
            v = fmaxf(v, 0.f);
            acc[mt][nt][j] = v;
            rs[j] += v; rq[j] += v*v;
          }
        }
        #pragma unroll
        for (int j = 0; j < 4; ++j){
          #pragma unroll
          for (int mm = 1; mm < 16; mm <<= 1){
            rs[j] += __shfl_xor(rs[j], mm, 64);
            rq[j] += __shfl_xor(rq[j], mm, 64);
          }
          float mu  = rs[j] * (1.f/128.f);
          float var = rq[j] * (1.f/128.f) - mu*mu;
          rs[j] = mu;
          rq[j] = rsqrtf(var + 1e-5f);
        }
        int rowb = rbase + mt*16 + g16*4;
        #pragma unroll
        for (int nt = 0; nt < 8; ++nt){
          int col = nt*16 + l15;
          float lg = lng_s[col], lb = lnb_s[col];
          #pragma unroll
          for (int j = 0; j < 4; ++j){
            float x = (acc[mt][nt][j] - rs[j]) * rq[j] * lg + lb;
            int row = rowb + j;
            Abuf[row*DM + (col ^ ((row & 7) << 3))] = f2b(x);
          }
        }
      }
    }

    // ---------- FFN in 4 chunks of 128 (all wave-local) ----------
    f32x4 c2[4][8];
    #pragma unroll
    for (int mt = 0; mt < 4; ++mt)
      #pragma unroll
      for (int nt = 0; nt < 8; ++nt){ f32x4 z; z[0]=z[1]=z[2]=z[3]=0.f; c2[mt][nt]=z; }
    #pragma unroll 1
    for (int c = 0; c < 4; ++c){
      // FFN1: Hc = relu(X @ W1c + b1c) -> hbuf (swizzled, own rows)
      f32x4 hc[4][8];
      #pragma unroll
      for (int mt = 0; mt < 4; ++mt)
        #pragma unroll
        for (int nt = 0; nt < 8; ++nt){ f32x4 z; z[0]=z[1]=z[2]=z[3]=0.f; hc[mt][nt]=z; }
      gemm64(Abuf, wsT + (l*9 + 1 + c)*16384, rbase, l15, g16, lane, hc);

      #pragma unroll
      for (int mt = 0; mt < 4; ++mt){
        int rowb = rbase + mt*16 + g16*4;
        #pragma unroll
        for (int nt = 0; nt < 8; ++nt){
          int col = nt*16 + l15;
          float bv = b1_s[c*128 + col];
          #pragma unroll
          for (int j = 0; j < 4; ++j){
            float v = fmaxf(hc[mt][nt][j] + bv, 0.f);
            int row = rowb + j;
            hbuf[row*DM + (col ^ ((row & 7) << 3))] = f2b(v);
          }
        }
      }
      // FFN2: c2 += Hc @ W2c  (same-wave LDS dep, compiler orders via lgkmcnt)
      gemm64(hbuf, wsT + (l*9 + 5 + c)*16384, rbase, l15, g16, lane, c2);
    }

    // ---------- Phase D: h = X + c2 + b2 -> hbuf natural (own rows) ----------
    #pragma unroll
    for (int mt = 0; mt < 4; ++mt){
      int rowb = rbase + mt*16 + g16*4;
      #pragma unroll
      for (int nt = 0; nt < 8; ++nt){
        int col = nt*16 + l15;
        float b2v = b2_s[col];
        #pragma unroll
        for (int j = 0; j < 4; ++j){
          int row = rowb + j;
          float x = b2f(Abuf[row*DM + (col ^ ((row & 7) << 3))]);
          hbuf[row*DM + col] = f2b(x + c2[mt][nt][j] + b2v);
        }
      }
    }
    __syncthreads();   // barrier B: h visible for next layer's agg / readout
  }

  // ---------------- readout ----------------
  {
    int gi = tid >> 3;
    int f0 = (tid & 7) * 16;
    if (gi < GPB && gi < nvalid) {
      float m[16];
      #pragma unroll
      for (int i = 0; i < 16; ++i) m[i] = 0.f;
      #pragma unroll
      for (int j = 0; j < NPG; ++j){
        bf16x8 h0 = *(const bf16x8*)&hbuf[(gi*NPG + j)*DM + f0];
        bf16x8 h1 = *(const bf16x8*)&hbuf[(gi*NPG + j)*DM + f0 + 8];
        #pragma unroll
        for (int i = 0; i < 8; ++i){
          m[i]   += b2f((unsigned short)h0[i]);
          m[i+8] += b2f((unsigned short)h1[i]);
        }
      }
      const float4* fw = (const float4*)&fcw[f0];
      float dot = 0.f;
      #pragma unroll
      for (int q = 0; q < 4; ++q){
        float4 wv = fw[q];
        dot += m[q*4+0]*wv.x + m[q*4+1]*wv.y + m[q*4+2]*wv.z + m[q*4+3]*wv.w;
      }
      dot *= (1.f/9.f);
      dot += __shfl_xor(dot, 1, 64);
      dot += __shfl_xor(dot, 2, 64);
      dot += __shfl_xor(dot, 4, 64);
      if ((tid & 7) == 0){
        float z = dot + fcb[0];
        out[g0 + gi] = 1.f / (1.f + __expf(-z));
      }
    }
  }
}

extern "C" void kernel_launch(void* const* d_in, const int* in_sizes, int n_in,
                              void* d_out, int out_size, void* d_ws, size_t ws_size,
                              hipStream_t stream)
{
  const float* op_table = (const float*)d_in[0];
  const float* dev_emb  = (const float*)d_in[1];
  const float* Wg  = (const float*)d_in[2];
  const float* bg  = (const float*)d_in[3];
  const float* lng = (const float*)d_in[4];
  const float* lnb = (const float*)d_in[5];
  const float* W1  = (const float*)d_in[6];
  const float* b1  = (const float*)d_in[7];
  const float* W2  = (const float*)d_in[8];
  const float* b2  = (const float*)d_in[9];
  const float* fcw = (const float*)d_in[10];
  const float* fcb = (const float*)d_in[11];
  const int* op_idx = (const int*)d_in[12];
  const int* srcA   = (const int*)d_in[13];
  const int* dstA   = (const int*)d_in[14];
  unsigned short* wsT = (unsigned short*)d_ws;

  wtr_kernel<<<288, 256, 0, stream>>>(Wg, W1, W2, wsT);
  gcn_kernel<<<NBLK, 256, 0, stream>>>(op_table, dev_emb, bg, lng, lnb, b1, b2,
                                       fcw, fcb, op_idx, srcA, dstA, wsT,
                                       (float*)d_out);
}

// Round 9
// 514.366 us; speedup vs baseline: 3.3288x; 3.3288x over previous
//
#include <hip/hip_runtime.h>
#include <hip/hip_bf16.h>

#define NGRAPH 16384
#define NPG    9
#define DM     128
#define HS     136   /* padded natural stride for hbuf (bank-conflict fix) */
#define NLAY   4
#define EPG    16
#define GPB    14
#define RPB    128
#define NBLK   1171   /* ceil(16384/14) */

typedef __attribute__((ext_vector_type(8))) short bf16x8;
typedef __attribute__((ext_vector_type(4))) float f32x4;

__device__ __forceinline__ float b2f(unsigned short u){
  union { unsigned int i; float f; } v; v.i = ((unsigned int)u) << 16; return v.f;
}
__device__ __forceinline__ unsigned short f2b(float f){
  union { float fv; unsigned int i; } v; v.fv = f;
  unsigned int r = v.i + 0x7FFFu + ((v.i >> 16) & 1u);
  return (unsigned short)(r >> 16);
}

struct Stg { f32x4 r[8]; };

__device__ __forceinline__ void stg_issue(Stg& s, const unsigned short* src, int tid){
  const f32x4* g = (const f32x4*)src;
  #pragma unroll
  for (int i = 0; i < 8; ++i) s.r[i] = g[i*256 + tid];
}
__device__ __forceinline__ void stg_write(const Stg& s, unsigned short* dst, int tid){
  f32x4* d = (f32x4*)dst;
  #pragma unroll
  for (int i = 0; i < 8; ++i) d[i*256 + tid] = s.r[i];
}

__device__ __forceinline__ bf16x8 ldfrag(const unsigned short* buf, int row, int kk, int g16){
  return *(const bf16x8*)&buf[row*DM + ((kk*32 + g16*8) ^ ((row & 7) << 3))];
}
__device__ __forceinline__ f32x4 mfma16(bf16x8 a, bf16x8 b, f32x4 c){
  return __builtin_amdgcn_mfma_f32_16x16x32_bf16(a, b, c, 0, 0, 0);
}

// Pre-transpose + convert f32->bf16 + swizzle weights into workspace:
// tiles (16384 bf16 each): per layer l: [0]=WgT, [1..4]=W1T chunk c (cols 128c..),
// [5..8]=W2T chunk c (k-rows 128c..). Element (n,k) stored at n*128 + (k ^ ((n&7)<<3)).
__global__ void wtr_kernel(const float* __restrict__ Wg,
                           const float* __restrict__ W1,
                           const float* __restrict__ W2,
                           unsigned short* __restrict__ wsT){
  int t = blockIdx.x * 256 + threadIdx.x;
  int tile = t >> 14;
  int e = t & 16383;
  int k = e >> 7;
  int n = e & 127;
  int l = tile / 9, t9 = tile - l*9;
  float v;
  if (t9 == 0)      v = Wg[l*16384 + k*128 + n];
  else if (t9 < 5)  v = W1[l*65536 + k*512 + (t9-1)*128 + n];
  else              v = W2[l*65536 + ((t9-5)*128 + k)*128 + n];
  wsT[tile*16384 + n*128 + (k ^ ((n & 7) << 3))] = f2b(v);
}

__global__ void __launch_bounds__(256, 1)
gcn_kernel(const float* __restrict__ op_table,
           const float* __restrict__ dev_emb,
           const float* __restrict__ bgp,
           const float* __restrict__ lngp,
           const float* __restrict__ lnbp,
           const float* __restrict__ b1p,
           const float* __restrict__ b2p,
           const float* __restrict__ fcw,
           const float* __restrict__ fcb,
           const int* __restrict__ op_idx,
           const int* __restrict__ srcA,
           const int* __restrict__ dstA,
           const unsigned short* __restrict__ wsT,
           float* __restrict__ out)
{
  __shared__ unsigned short hbuf[RPB*HS];      // natural h (stride 136); aliased as swizzled Hc (stride 128) in FFN
  __shared__ unsigned short Abuf[RPB*DM];      // swizzled A operand (agg, then X)
  __shared__ unsigned short Wbuf[2][DM*DM];    // double-buffered weight tile
  __shared__ float cntF[GPB][81];              // normalized adjacency (isd folded)
  __shared__ float isd_s[RPB];
  __shared__ float bg_s[DM], lng_s[DM], lnb_s[DM], b2_s[DM];
  __shared__ float b1_s[4*DM];

  const int tid  = threadIdx.x;
  const int w    = tid >> 6;
  const int lane = tid & 63;
  const int g16  = lane >> 4;
  const int l15  = lane & 15;
  const int rbase = w * 32;
  const int g0 = blockIdx.x * GPB;
  const int nvalid = (NGRAPH - g0 < GPB) ? (NGRAPH - g0) : GPB;

  // ---------------- preamble ----------------
  for (int i = tid; i < GPB*81; i += 256) (&cntF[0][0])[i] = 0.f;

  { // h0 = op_table[idx] + device_emb (f32 -> bf16) ; zeros for pad/invalid rows
    int r  = tid >> 1;
    int fh = (tid & 1) * 64;
    int gi = r / NPG;
    int j  = r - gi*NPG;
    bf16x8* dstp = (bf16x8*)&hbuf[r*HS + fh];
    if (r < GPB*NPG && gi < nvalid) {
      int idx = op_idx[(g0 + gi)*NPG + j];
      const float4* ot = (const float4*)&op_table[idx*DM + fh];
      const float4* de = (const float4*)&dev_emb[fh];
      #pragma unroll
      for (int i = 0; i < 8; ++i){
        float4 a0 = ot[2*i], a1 = ot[2*i+1];
        float4 d0 = de[2*i], d1 = de[2*i+1];
        bf16x8 o;
        o[0] = (short)f2b(a0.x + d0.x); o[1] = (short)f2b(a0.y + d0.y);
        o[2] = (short)f2b(a0.z + d0.z); o[3] = (short)f2b(a0.w + d0.w);
        o[4] = (short)f2b(a1.x + d1.x); o[5] = (short)f2b(a1.y + d1.y);
        o[6] = (short)f2b(a1.z + d1.z); o[7] = (short)f2b(a1.w + d1.w);
        dstp[i] = o;
      }
    } else if (r < RPB) {
      bf16x8 z;
      #pragma unroll
      for (int q = 0; q < 8; ++q) z[q] = 0;
      #pragma unroll
      for (int i = 0; i < 8; ++i) dstp[i] = z;
    }
  }
  __syncthreads();

  if (tid < GPB && tid < nvalid) { // per-graph 9x9 count matrix (incl. self loops)
    float* c = cntF[tid];
    for (int e = 0; e < EPG; ++e){
      int s = srcA[(g0 + tid)*EPG + e];
      int d = dstA[(g0 + tid)*EPG + e];
      c[(s % NPG)*NPG + (d % NPG)] += 1.f;
    }
    #pragma unroll
    for (int j = 0; j < NPG; ++j) c[j*NPG + j] += 1.f;
  }
  __syncthreads();

  if (tid < RPB) { // deg = column sums of cnt ; isd = rsqrt(deg)
    int gi = tid / NPG;
    if (tid < GPB*NPG && gi < nvalid) {
      int jd = tid - gi*NPG;
      float s = 0.f;
      #pragma unroll
      for (int js = 0; js < NPG; ++js) s += cntF[gi][js*NPG + jd];
      isd_s[tid] = rsqrtf(s);
    } else isd_s[tid] = 1.f;
  }
  __syncthreads();

  { // fold isd into cnt: cnt'[js][jd] = cnt * isd[js] * isd[jd]; stage Wg[0]
    Stg s0;
    stg_issue(s0, wsT, tid);
    for (int idx = tid; idx < GPB*81; idx += 256){
      int gi = idx / 81;
      int e  = idx - gi*81;
      int js = e / 9, jd = e - js*9;
      (&cntF[0][0])[idx] *= isd_s[gi*NPG + js] * isd_s[gi*NPG + jd];
    }
    stg_write(s0, Wbuf[0], tid);
  }
  __syncthreads();

  f32x4 Xres[2][8];
  Stg sA, sB;

  #pragma unroll 1
  for (int l = 0; l < NLAY; ++l){
    // ---------- Phase A: aggregation -> Abuf ----------
    if (l > 0) stg_write(sB, Wbuf[0], tid);          // Wg[l] (issued at prev layer c==3)
    stg_issue(sA, wsT + (l*9 + 1)*16384, tid);       // W1 chunk 0
    if (tid < DM) {
      bg_s[tid]  = bgp [l*DM + tid];
      lng_s[tid] = lngp[l*DM + tid];
      lnb_s[tid] = lnbp[l*DM + tid];
      b2_s[tid]  = b2p [l*DM + tid];
    }
    b1_s[tid]       = b1p[l*4*DM + tid];
    b1_s[tid + 256] = b1p[l*4*DM + 256 + tid];
    {
      int gi = tid >> 4;
      int f0 = (tid & 15) * 8;
      if (gi < GPB) {
        float hs[NPG][8];
        #pragma unroll
        for (int j = 0; j < NPG; ++j){
          bf16x8 hv = *(const bf16x8*)&hbuf[(gi*NPG + j)*HS + f0];
          #pragma unroll
          for (int i = 0; i < 8; ++i) hs[j][i] = b2f((unsigned short)hv[i]);
        }
        #pragma unroll
        for (int jd = 0; jd < NPG; ++jd){
          float av[8];
          #pragma unroll
          for (int i = 0; i < 8; ++i) av[i] = 0.f;
          #pragma unroll
          for (int js = 0; js < NPG; ++js){
            float cc = cntF[gi][js*NPG + jd];
            #pragma unroll
            for (int i = 0; i < 8; ++i) av[i] = fmaf(cc, hs[js][i], av[i]);
          }
          int row = gi*NPG + jd;
          bf16x8 o;
          #pragma unroll
          for (int i = 0; i < 8; ++i) o[i] = (short)f2b(av[i]);
          *(bf16x8*)&Abuf[row*DM + (f0 ^ ((row & 7) << 3))] = o;
        }
      } else { // zero pad rows 126,127 (write all 16 segs -> whole rows zero)
        int k2 = tid - 224;
        int row = 126 + (k2 >> 4);
        int seg = (k2 & 15) * 8;
        bf16x8 z;
        #pragma unroll
        for (int q = 0; q < 8; ++q) z[q] = 0;
        *(bf16x8*)&Abuf[row*DM + seg] = z;
      }
    }
    stg_write(sA, Wbuf[1], tid);                     // W1 chunk 0 -> buf1
    __syncthreads();

    // ---------- Phase B: X = LN(relu(agg @ Wg + bg)) ----------
    stg_issue(sB, wsT + (l*9 + 5)*16384, tid);       // W2 chunk 0
    f32x4 acc[2][8];
    #pragma unroll
    for (int mt = 0; mt < 2; ++mt)
      #pragma unroll
      for (int nt = 0; nt < 8; ++nt){ f32x4 z; z[0]=z[1]=z[2]=z[3]=0.f; acc[mt][nt]=z; }
    #pragma unroll
    for (int kk = 0; kk < 4; ++kk){
      bf16x8 a0 = ldfrag(Abuf, rbase + l15, kk, g16);
      bf16x8 a1 = ldfrag(Abuf, rbase + 16 + l15, kk, g16);
      #pragma unroll
      for (int nt = 0; nt < 8; ++nt){
        bf16x8 bb = ldfrag(Wbuf[0], nt*16 + l15, kk, g16);
        acc[0][nt] = mfma16(a0, bb, acc[0][nt]);
        acc[1][nt] = mfma16(a1, bb, acc[1][nt]);
      }
    }
    #pragma unroll
    for (int mt = 0; mt < 2; ++mt){
      float rs[4], rq[4];
      #pragma unroll
      for (int j = 0; j < 4; ++j){ rs[j] = 0.f; rq[j] = 0.f; }
      #pragma unroll
      for (int nt = 0; nt < 8; ++nt){
        #pragma unroll
        for (int j = 0; j < 4; ++j){
          float v = acc[mt][nt][j] + bg_s[nt*16 + l15];
          v = fmaxf(v, 0.f);
          acc[mt][nt][j] = v;
          rs[j] += v; rq[j] += v*v;
        }
      }
      #pragma unroll
      for (int j = 0; j < 4; ++j){
        #pragma unroll
        for (int mm = 1; mm < 16; mm <<= 1){
          rs[j] += __shfl_xor(rs[j], mm, 64);
          rq[j] += __shfl_xor(rq[j], mm, 64);
        }
        float mu  = rs[j] * (1.f/128.f);
        float var = rq[j] * (1.f/128.f) - mu*mu;
        rs[j] = mu;
        rq[j] = rsqrtf(var + 1e-5f);
      }
      int rowb = rbase + mt*16 + g16*4;
      #pragma unroll
      for (int nt = 0; nt < 8; ++nt){
        int col = nt*16 + l15;
        float lg = lng_s[col], lb = lnb_s[col];
        #pragma unroll
        for (int j = 0; j < 4; ++j){
          float x = (acc[mt][nt][j] - rs[j]) * rq[j] * lg + lb;
          Xres[mt][nt][j] = x;
          int row = rowb + j;
          Abuf[row*DM + (col ^ ((row & 7) << 3))] = f2b(x);
        }
      }
    }
    __syncthreads();

    // ---------- FFN in 4 chunks of 128 ----------
    f32x4 c2[2][8];
    #pragma unroll
    for (int mt = 0; mt < 2; ++mt)
      #pragma unroll
      for (int nt = 0; nt < 8; ++nt){ f32x4 z; z[0]=z[1]=z[2]=z[3]=0.f; c2[mt][nt]=z; }
    #pragma unroll 1
    for (int c = 0; c < 4; ++c){
      stg_write(sB, Wbuf[0], tid);                                  // W2 chunk c
      if (c < 3)      stg_issue(sA, wsT + (l*9 + 2 + c)*16384, tid); // W1 chunk c+1
      else if (l < 3) stg_issue(sB, wsT + ((l+1)*9)*16384, tid);     // Wg[l+1]

      // FFN1: Hc = relu(X @ W1c + b1c) -> hbuf (swizzled stride-128, own rows)
      f32x4 hc[2][8];
      #pragma unroll
      for (int mt = 0; mt < 2; ++mt)
        #pragma unroll
        for (int nt = 0; nt < 8; ++nt){ f32x4 z; z[0]=z[1]=z[2]=z[3]=0.f; hc[mt][nt]=z; }
      #pragma unroll
      for (int kk = 0; kk < 4; ++kk){
        bf16x8 a0 = ldfrag(Abuf, rbase + l15, kk, g16);
        bf16x8 a1 = ldfrag(Abuf, rbase + 16 + l15, kk, g16);
        #pragma unroll
        for (int nt = 0; nt < 8; ++nt){
          bf16x8 bb = ldfrag(Wbuf[1], nt*16 + l15, kk, g16);
          hc[0][nt] = mfma16(a0, bb, hc[0][nt]);
          hc[1][nt] = mfma16(a1, bb, hc[1][nt]);
        }
      }
      #pragma unroll
      for (int mt = 0; mt < 2; ++mt){
        int rowb = rbase + mt*16 + g16*4;
        #pragma unroll
        for (int nt = 0; nt < 8; ++nt){
          int col = nt*16 + l15;
          float bv = b1_s[c*128 + col];
          #pragma unroll
          for (int j = 0; j < 4; ++j){
            float v = fmaxf(hc[mt][nt][j] + bv, 0.f);
            int row = rowb + j;
            hbuf[row*DM + (col ^ ((row & 7) << 3))] = f2b(v);
          }
        }
      }
      __syncthreads();

      if (c < 3){ stg_write(sA, Wbuf[1], tid); stg_issue(sB, wsT + (l*9 + 6 + c)*16384, tid); }

      // FFN2: c2 += Hc @ W2c
      #pragma unroll
      for (int kk = 0; kk < 4; ++kk){
        bf16x8 a0 = ldfrag(hbuf, rbase + l15, kk, g16);
        bf16x8 a1 = ldfrag(hbuf, rbase + 16 + l15, kk, g16);
        #pragma unroll
        for (int nt = 0; nt < 8; ++nt){
          bf16x8 bb = ldfrag(Wbuf[0], nt*16 + l15, kk, g16);
          c2[0][nt] = mfma16(a0, bb, c2[0][nt]);
          c2[1][nt] = mfma16(a1, bb, c2[1][nt]);
        }
      }
      __syncthreads();
    }

    // ---------- Phase D: h = X + c2 + b2 -> hbuf natural (stride 136, own rows) ----------
    #pragma unroll
    for (int mt = 0; mt < 2; ++mt){
      int rowb = rbase + mt*16 + g16*4;
      #pragma unroll
      for (int nt = 0; nt < 8; ++nt){
        int col = nt*16 + l15;
        float b2v = b2_s[col];
        #pragma unroll
        for (int j = 0; j < 4; ++j){
          int row = rowb + j;
          hbuf[row*HS + col] = f2b(Xres[mt][nt][j] + c2[mt][nt][j] + b2v);
        }
      }
    }
    __syncthreads();   // barrier B: h visible for next layer's agg / readout
  }

  // ---------------- readout ----------------
  {
    int gi = tid >> 4;
    int f0 = (tid & 15) * 8;
    if (gi < nvalid) {
      float m[8];
      #pragma unroll
      for (int i = 0; i < 8; ++i) m[i] = 0.f;
      #pragma unroll
      for (int j = 0; j < NPG; ++j){
        bf16x8 hv = *(const bf16x8*)&hbuf[(gi*NPG + j)*HS + f0];
        #pragma unroll
        for (int i = 0; i < 8; ++i) m[i] += b2f((unsigned short)hv[i]);
      }
      const float4* fw = (const float4*)&fcw[f0];
      float4 w0 = fw[0], w1 = fw[1];
      float dot = m[0]*w0.x + m[1]*w0.y + m[2]*w0.z + m[3]*w0.w
                + m[4]*w1.x + m[5]*w1.y + m[6]*w1.z + m[7]*w1.w;
      dot *= (1.f/9.f);
      #pragma unroll
      for (int mm = 1; mm < 16; mm <<= 1) dot += __shfl_xor(dot, mm, 64);
      if ((tid & 15) == 0){
        float z = dot + fcb[0];
        out[g0 + gi] = 1.f / (1.f + __expf(-z));
      }
    }
  }
}

extern "C" void kernel_launch(void* const* d_in, const int* in_sizes, int n_in,
                              void* d_out, int out_size, void* d_ws, size_t ws_size,
                              hipStream_t stream)
{
  const float* op_table = (const float*)d_in[0];
  const float* dev_emb  = (const float*)d_in[1];
  const float* Wg  = (const float*)d_in[2];
  const float* bg  = (const float*)d_in[3];
  const float* lng = (const float*)d_in[4];
  const float* lnb = (const float*)d_in[5];
  const float* W1  = (const float*)d_in[6];
  const float* b1  = (const float*)d_in[7];
  const float* W2  = (const float*)d_in[8];
  const float* b2  = (const float*)d_in[9];
  const float* fcw = (const float*)d_in[10];
  const float* fcb = (const float*)d_in[11];
  const int* op_idx = (const int*)d_in[12];
  const int* srcA   = (const int*)d_in[13];
  const int* dstA   = (const int*)d_in[14];
  unsigned short* wsT = (unsigned short*)d_ws;

  wtr_kernel<<<2304, 256, 0, stream>>>(Wg, W1, W2, wsT);
  gcn_kernel<<<NBLK, 256, 0, stream>>>(op_table, dev_emb, bg, lng, lnb, b1, b2,
                                       fcw, fcb, op_idx, srcA, dstA, wsT,
                                       (float*)d_out);
}

// Round 10
// 360.987 us; speedup vs baseline: 4.7432x; 1.4249x over previous
//
#include <hip/hip_runtime.h>

#define NGRAPH 16384
#define NPG    9
#define DM     128
#define NLAY   4
#define EPG    16
#define GPB    14
#define RPB    128
#define NBLK   1171   /* ceil(16384/14) */

typedef __attribute__((ext_vector_type(8))) short bf16x8;
typedef __attribute__((ext_vector_type(4))) float f32x4;

__device__ __forceinline__ float b2f(unsigned short u){
  union { unsigned int i; float f; } v; v.i = ((unsigned int)u) << 16; return v.f;
}
__device__ __forceinline__ unsigned short f2b(float f){
  union { float fv; unsigned int i; } v; v.fv = f;
  unsigned int r = v.i + 0x7FFFu + ((v.i >> 16) & 1u);
  return (unsigned short)(r >> 16);
}

__device__ __forceinline__ bf16x8 ldfrag128(const unsigned short* buf, int row, int kk, int g16){
  return *(const bf16x8*)&buf[row*DM + ((kk*32 + g16*8) ^ ((row & 7) << 3))];
}
__device__ __forceinline__ bf16x8 ldfrag64(const unsigned short* buf, int row, int kk, int g16){
  return *(const bf16x8*)&buf[row*64 + ((kk*32 + g16*8) ^ ((row & 7) << 3))];
}
__device__ __forceinline__ f32x4 mfma16(bf16x8 a, bf16x8 b, f32x4 c){
  return __builtin_amdgcn_mfma_f32_16x16x32_bf16(a, b, c, 0, 0, 0);
}
// stage one 16-KB weight tile (8192 bf16) with 256 threads
__device__ __forceinline__ void stage_w(const unsigned short* __restrict__ src,
                                        unsigned short* __restrict__ dst, int tid){
  const f32x4* g = (const f32x4*)src;
  f32x4* d = (f32x4*)dst;
  f32x4 v0 = g[tid], v1 = g[256 + tid], v2 = g[512 + tid], v3 = g[768 + tid];
  d[tid] = v0; d[256 + tid] = v1; d[512 + tid] = v2; d[768 + tid] = v3;
}

// Weight pre-transform: f32 -> bf16, transposed, XOR-swizzled, 16-KB tiles.
// Per layer l (18 tiles of 8192 bf16 each, base (l*18+s)*8192):
//  s=0,1  : WgT k-half s   -> tile[n*64  + (kl ^ ((n &7)<<3))],  n 0..127, kl 0..63, k = s*64+kl
//  s=2..9 : W1T col-chunk  -> tile[nl*128 + (k  ^ ((nl&7)<<3))], nl 0..63, k 0..127, n = (s-2)*64+nl
//  s=10..17: W2T k-chunk   -> tile[n*64  + (kl ^ ((n &7)<<3))],  n 0..127, kl 0..63, k = (s-10)*64+kl
__global__ void wtr_kernel(const float* __restrict__ Wg,
                           const float* __restrict__ W1,
                           const float* __restrict__ W2,
                           unsigned short* __restrict__ wsT){
  int idx = blockIdx.x * 256 + threadIdx.x;   // 2304 blocks -> 589824 = 72*8192
  int t = idx >> 13;
  int e = idx & 8191;
  int l = t / 18, s = t - l*18;
  if (s < 2){
    int n = e & 127, kl = e >> 7;
    float v = Wg[l*16384 + (s*64 + kl)*128 + n];
    wsT[t*8192 + n*64 + (kl ^ ((n & 7) << 3))] = f2b(v);
  } else if (s < 10){
    int nl = e & 63, k = e >> 6;
    float v = W1[l*65536 + k*512 + (s-2)*64 + nl];
    wsT[t*8192 + nl*128 + (k ^ ((nl & 7) << 3))] = f2b(v);
  } else {
    int n = e & 127, kl = e >> 7;
    float v = W2[l*65536 + ((s-10)*64 + kl)*128 + n];
    wsT[t*8192 + n*64 + (kl ^ ((n & 7) << 3))] = f2b(v);
  }
}

__global__ void __launch_bounds__(256, 2)
gcn_kernel(const float* __restrict__ op_table,
           const float* __restrict__ dev_emb,
           const float* __restrict__ bgp,
           const float* __restrict__ lngp,
           const float* __restrict__ lnbp,
           const float* __restrict__ b1p,
           const float* __restrict__ b2p,
           const float* __restrict__ fcw,
           const float* __restrict__ fcb,
           const int* __restrict__ op_idx,
           const int* __restrict__ srcA,
           const int* __restrict__ dstA,
           const unsigned short* __restrict__ wsT,
           float* __restrict__ out)
{
  __shared__ unsigned short H[RPB*DM];   // 32 KB: h / agg / X, swizzled stride-128
  __shared__ unsigned short Cb[RPB*64];  // 16 KB: Hc chunk, swizzled stride-64
  __shared__ unsigned short Wb[8192];    // 16 KB: current weight tile
  __shared__ float cntF[GPB][81];        // normalized adjacency (isd folded)
  __shared__ float isd_s[RPB];
  __shared__ float bg_s[DM], lng_s[DM], lnb_s[DM], b2_s[DM];
  __shared__ float b1_s[4*DM];

  const int tid  = threadIdx.x;
  const int w    = tid >> 6;
  const int lane = tid & 63;
  const int g16  = lane >> 4;
  const int l15  = lane & 15;
  const int rbase = w * 32;
  const int g0 = blockIdx.x * GPB;
  const int nvalid = (NGRAPH - g0 < GPB) ? (NGRAPH - g0) : GPB;

  // ---------------- preamble ----------------
  for (int i = tid; i < GPB*81; i += 256) (&cntF[0][0])[i] = 0.f;

  { // h0 = op_table[idx] + device_emb -> H swizzled; zeros for pad/invalid rows
    int r  = tid >> 1;
    int gh = (tid & 1) * 8;           // group base 0 or 8 (each group = 8 elems)
    int gi = r / NPG;
    int j  = r - gi*NPG;
    if (r < GPB*NPG && gi < nvalid) {
      int idx = op_idx[(g0 + gi)*NPG + j];
      const float4* ot = (const float4*)&op_table[idx*DM + gh*8];
      const float4* de = (const float4*)&dev_emb[gh*8];
      #pragma unroll
      for (int i = 0; i < 8; ++i){
        float4 a0 = ot[2*i], a1 = ot[2*i+1];
        float4 d0 = de[2*i], d1 = de[2*i+1];
        bf16x8 o;
        o[0] = (short)f2b(a0.x + d0.x); o[1] = (short)f2b(a0.y + d0.y);
        o[2] = (short)f2b(a0.z + d0.z); o[3] = (short)f2b(a0.w + d0.w);
        o[4] = (short)f2b(a1.x + d1.x); o[5] = (short)f2b(a1.y + d1.y);
        o[6] = (short)f2b(a1.z + d1.z); o[7] = (short)f2b(a1.w + d1.w);
        int g = gh + i;
        *(bf16x8*)&H[r*DM + ((g ^ (r & 7)) << 3)] = o;
      }
    } else {
      bf16x8 z;
      #pragma unroll
      for (int q = 0; q < 8; ++q) z[q] = 0;
      #pragma unroll
      for (int i = 0; i < 8; ++i){
        int g = gh + i;
        *(bf16x8*)&H[r*DM + ((g ^ (r & 7)) << 3)] = z;
      }
    }
  }
  __syncthreads();

  if (tid < GPB && tid < nvalid) { // 9x9 count matrix incl. self loops
    float* c = cntF[tid];
    for (int e = 0; e < EPG; ++e){
      int s = srcA[(g0 + tid)*EPG + e];
      int d = dstA[(g0 + tid)*EPG + e];
      c[(s % NPG)*NPG + (d % NPG)] += 1.f;
    }
    #pragma unroll
    for (int j = 0; j < NPG; ++j) c[j*NPG + j] += 1.f;
  }
  __syncthreads();

  if (tid < RPB) { // isd = rsqrt(column sums)
    int gi = tid / NPG;
    if (tid < GPB*NPG && gi < nvalid) {
      int jd = tid - gi*NPG;
      float s = 0.f;
      #pragma unroll
      for (int js = 0; js < NPG; ++js) s += cntF[gi][js*NPG + jd];
      isd_s[tid] = rsqrtf(s);
    } else isd_s[tid] = 1.f;
  }
  __syncthreads();

  for (int idx = tid; idx < GPB*81; idx += 256){ // fold isd into cnt
    int gi = idx / 81;
    int e  = idx - gi*81;
    int js = e / 9, jd = e - js*9;
    (&cntF[0][0])[idx] *= isd_s[gi*NPG + js] * isd_s[gi*NPG + jd];
  }
  __syncthreads();

  #pragma unroll 1
  for (int l = 0; l < NLAY; ++l){
    // ---------- Phase A: stage Wg-half0 + biases + in-place agg on H ----------
    stage_w(wsT + (l*18 + 0)*8192, Wb, tid);
    if (tid < DM) {
      bg_s[tid]  = bgp [l*DM + tid];
      lng_s[tid] = lngp[l*DM + tid];
      lnb_s[tid] = lnbp[l*DM + tid];
      b2_s[tid]  = b2p [l*DM + tid];
    }
    b1_s[tid]       = b1p[l*4*DM + tid];
    b1_s[tid + 256] = b1p[l*4*DM + 256 + tid];
    {
      int gi = tid >> 4;
      int g  = tid & 15;
      if (gi < GPB) {
        float hs[NPG][8];
        #pragma unroll
        for (int j = 0; j < NPG; ++j){
          int row = gi*NPG + j;
          bf16x8 hv = *(const bf16x8*)&H[row*DM + ((g ^ (row & 7)) << 3)];
          #pragma unroll
          for (int i = 0; i < 8; ++i) hs[j][i] = b2f((unsigned short)hv[i]);
        }
        #pragma unroll
        for (int jd = 0; jd < NPG; ++jd){
          float av[8];
          #pragma unroll
          for (int i = 0; i < 8; ++i) av[i] = 0.f;
          #pragma unroll
          for (int js = 0; js < NPG; ++js){
            float cc = cntF[gi][js*NPG + jd];
            #pragma unroll
            for (int i = 0; i < 8; ++i) av[i] = fmaf(cc, hs[js][i], av[i]);
          }
          int row = gi*NPG + jd;
          bf16x8 o;
          #pragma unroll
          for (int i = 0; i < 8; ++i) o[i] = (short)f2b(av[i]);
          *(bf16x8*)&H[row*DM + ((g ^ (row & 7)) << 3)] = o;
        }
      } else { // zero pad rows 126,127
        int k2 = tid - GPB*16;
        int row = GPB*NPG + (k2 >> 4);
        int gg = k2 & 15;
        bf16x8 z;
        #pragma unroll
        for (int q = 0; q < 8; ++q) z[q] = 0;
        *(bf16x8*)&H[row*DM + ((gg ^ (row & 7)) << 3)] = z;
      }
    }
    __syncthreads();   // bar1: agg + Wg-h0 + biases visible

    // ---------- GCN GEMM (K split in 2 halves) + ReLU + LN -> X in H ----------
    f32x4 acc[2][8];
    #pragma unroll
    for (int mt = 0; mt < 2; ++mt)
      #pragma unroll
      for (int nt = 0; nt < 8; ++nt){ f32x4 z; z[0]=z[1]=z[2]=z[3]=0.f; acc[mt][nt]=z; }
    #pragma unroll
    for (int kk = 0; kk < 2; ++kk){
      bf16x8 a0 = ldfrag128(H, rbase + l15, kk, g16);
      bf16x8 a1 = ldfrag128(H, rbase + 16 + l15, kk, g16);
      __builtin_amdgcn_s_setprio(1);
      #pragma unroll
      for (int nt = 0; nt < 8; ++nt){
        bf16x8 bb = ldfrag64(Wb, nt*16 + l15, kk, g16);
        acc[0][nt] = mfma16(a0, bb, acc[0][nt]);
        acc[1][nt] = mfma16(a1, bb, acc[1][nt]);
      }
      __builtin_amdgcn_s_setprio(0);
    }
    __syncthreads();   // bar2: Wb(Wg-h0) reads done
    stage_w(wsT + (l*18 + 1)*8192, Wb, tid);
    __syncthreads();   // bar3: Wg-h1 staged
    #pragma unroll
    for (int kk = 0; kk < 2; ++kk){
      bf16x8 a0 = ldfrag128(H, rbase + l15, 2 + kk, g16);
      bf16x8 a1 = ldfrag128(H, rbase + 16 + l15, 2 + kk, g16);
      __builtin_amdgcn_s_setprio(1);
      #pragma unroll
      for (int nt = 0; nt < 8; ++nt){
        bf16x8 bb = ldfrag64(Wb, nt*16 + l15, kk, g16);
        acc[0][nt] = mfma16(a0, bb, acc[0][nt]);
        acc[1][nt] = mfma16(a1, bb, acc[1][nt]);
      }
      __builtin_amdgcn_s_setprio(0);
    }
    // LN epilogue -> X written swizzled into H (wave-own rows, in place over agg)
    #pragma unroll
    for (int mt = 0; mt < 2; ++mt){
      float rs[4], rq[4];
      #pragma unroll
      for (int j = 0; j < 4; ++j){ rs[j] = 0.f; rq[j] = 0.f; }
      #pragma unroll
      for (int nt = 0; nt < 8; ++nt){
        #pragma unroll
        for (int j = 0; j < 4; ++j){
          float v = acc[mt][nt][j] + bg_s[nt*16 + l15];
          v = fmaxf(v, 0.f);
          acc[mt][nt][j] = v;
          rs[j] += v; rq[j] += v*v;
        }
      }
      #pragma unroll
      for (int j = 0; j < 4; ++j){
        #pragma unroll
        for (int mm = 1; mm < 16; mm <<= 1){
          rs[j] += __shfl_xor(rs[j], mm, 64);
          rq[j] += __shfl_xor(rq[j], mm, 64);
        }
        float mu  = rs[j] * (1.f/128.f);
        float var = rq[j] * (1.f/128.f) - mu*mu;
        rs[j] = mu;
        rq[j] = rsqrtf(var + 1e-5f);
      }
      int rowb = rbase + mt*16 + g16*4;
      #pragma unroll
      for (int nt = 0; nt < 8; ++nt){
        int col = nt*16 + l15;
        float lg = lng_s[col], lb = lnb_s[col];
        #pragma unroll
        for (int j = 0; j < 4; ++j){
          float x = (acc[mt][nt][j] - rs[j]) * rq[j] * lg + lb;
          int row = rowb + j;
          H[row*DM + (col ^ ((row & 7) << 3))] = f2b(x);
        }
      }
    }
    __syncthreads();   // bar4: Wg-h1 reads done (Wb free)

    // ---------- FFN in 8 chunks of 64 hidden ----------
    f32x4 c2[2][8];
    #pragma unroll
    for (int mt = 0; mt < 2; ++mt)
      #pragma unroll
      for (int nt = 0; nt < 8; ++nt){ f32x4 z; z[0]=z[1]=z[2]=z[3]=0.f; c2[mt][nt]=z; }
    #pragma unroll 1
    for (int c = 0; c < 8; ++c){
      stage_w(wsT + (l*18 + 2 + c)*8192, Wb, tid);      // W1 chunk c
      __syncthreads();  // barA
      // FFN1: Hc = relu(X @ W1c + b1c) -> Cb (stride 64, own rows)
      f32x4 hc[2][4];
      #pragma unroll
      for (int mt = 0; mt < 2; ++mt)
        #pragma unroll
        for (int nt = 0; nt < 4; ++nt){ f32x4 z; z[0]=z[1]=z[2]=z[3]=0.f; hc[mt][nt]=z; }
      #pragma unroll
      for (int kk = 0; kk < 4; ++kk){
        bf16x8 a0 = ldfrag128(H, rbase + l15, kk, g16);
        bf16x8 a1 = ldfrag128(H, rbase + 16 + l15, kk, g16);
        __builtin_amdgcn_s_setprio(1);
        #pragma unroll
        for (int nt = 0; nt < 4; ++nt){
          bf16x8 bb = ldfrag128(Wb, nt*16 + l15, kk, g16);
          hc[0][nt] = mfma16(a0, bb, hc[0][nt]);
          hc[1][nt] = mfma16(a1, bb, hc[1][nt]);
        }
        __builtin_amdgcn_s_setprio(0);
      }
      #pragma unroll
      for (int mt = 0; mt < 2; ++mt){
        int rowb = rbase + mt*16 + g16*4;
        #pragma unroll
        for (int nt = 0; nt < 4; ++nt){
          int col = nt*16 + l15;
          float bv = b1_s[c*64 + col];
          #pragma unroll
          for (int j = 0; j < 4; ++j){
            float v = fmaxf(hc[mt][nt][j] + bv, 0.f);
            int row = rowb + j;
            Cb[row*64 + (col ^ ((row & 7) << 3))] = f2b(v);
          }
        }
      }
      __syncthreads();  // barB: Wb(W1c) reads done
      stage_w(wsT + (l*18 + 10 + c)*8192, Wb, tid);     // W2 chunk c
      __syncthreads();  // barC
      // FFN2: c2 += Hc @ W2c
      #pragma unroll
      for (int kk = 0; kk < 2; ++kk){
        bf16x8 a0 = ldfrag64(Cb, rbase + l15, kk, g16);
        bf16x8 a1 = ldfrag64(Cb, rbase + 16 + l15, kk, g16);
        __builtin_amdgcn_s_setprio(1);
        #pragma unroll
        for (int nt = 0; nt < 8; ++nt){
          bf16x8 bb = ldfrag64(Wb, nt*16 + l15, kk, g16);
          c2[0][nt] = mfma16(a0, bb, c2[0][nt]);
          c2[1][nt] = mfma16(a1, bb, c2[1][nt]);
        }
        __builtin_amdgcn_s_setprio(0);
      }
      __syncthreads();  // barD: Wb(W2c) reads done
    }

    // ---------- Phase D: h = X + c2 + b2 -> H (in place, own rows) ----------
    #pragma unroll
    for (int mt = 0; mt < 2; ++mt){
      int rowb = rbase + mt*16 + g16*4;
      #pragma unroll
      for (int nt = 0; nt < 8; ++nt){
        int col = nt*16 + l15;
        float b2v = b2_s[col];
        #pragma unroll
        for (int j = 0; j < 4; ++j){
          int row = rowb + j;
          int p = row*DM + (col ^ ((row & 7) << 3));
          float x = b2f(H[p]);
          H[p] = f2b(x + c2[mt][nt][j] + b2v);
        }
      }
    }
    __syncthreads();   // barE: h visible for next layer / readout
  }

  // ---------------- readout ----------------
  {
    int gi = tid >> 4;
    int g  = tid & 15;
    if (gi < nvalid) {
      float m[8];
      #pragma unroll
      for (int i = 0; i < 8; ++i) m[i] = 0.f;
      #pragma unroll
      for (int j = 0; j < NPG; ++j){
        int row = gi*NPG + j;
        bf16x8 hv = *(const bf16x8*)&H[row*DM + ((g ^ (row & 7)) << 3)];
        #pragma unroll
        for (int i = 0; i < 8; ++i) m[i] += b2f((unsigned short)hv[i]);
      }
      const float4* fw = (const float4*)&fcw[g*8];
      float4 w0 = fw[0], w1 = fw[1];
      float dot = m[0]*w0.x + m[1]*w0.y + m[2]*w0.z + m[3]*w0.w
                + m[4]*w1.x + m[5]*w1.y + m[6]*w1.z + m[7]*w1.w;
      dot *= (1.f/9.f);
      #pragma unroll
      for (int mm = 1; mm < 16; mm <<= 1) dot += __shfl_xor(dot, mm, 64);
      if ((tid & 15) == 0){
        float z = dot + fcb[0];
        out[g0 + gi] = 1.f / (1.f + __expf(-z));
      }
    }
  }
}

extern "C" void kernel_launch(void* const* d_in, const int* in_sizes, int n_in,
                              void* d_out, int out_size, void* d_ws, size_t ws_size,
                              hipStream_t stream)
{
  const float* op_table = (const float*)d_in[0];
  const float* dev_emb  = (const float*)d_in[1];
  const float* Wg  = (const float*)d_in[2];
  const float* bg  = (const float*)d_in[3];
  const float* lng = (const float*)d_in[4];
  const float* lnb = (const float*)d_in[5];
  const float* W1  = (const float*)d_in[6];
  const float* b1  = (const float*)d_in[7];
  const float* W2  = (const float*)d_in[8];
  const float* b2  = (const float*)d_in[9];
  const float* fcw = (const float*)d_in[10];
  const float* fcb = (const float*)d_in[11];
  const int* op_idx = (const int*)d_in[12];
  const int* srcA   = (const int*)d_in[13];
  const int* dstA   = (const int*)d_in[14];
  unsigned short* wsT = (unsigned short*)d_ws;

  wtr_kernel<<<2304, 256, 0, stream>>>(Wg, W1, W2, wsT);
  gcn_kernel<<<NBLK, 256, 0, stream>>>(op_table, dev_emb, bg, lng, lnb, b1, b2,
                                       fcw, fcb, op_idx, srcA, dstA, wsT,
                                       (float*)d_out);
}